// Round 1
// baseline (1529.164 us; speedup 1.0000x reference)
//
#include <hip/hip_runtime.h>
#include <math.h>

// Problem constants (from reference): B=4, N=4096 -> 16384 windows
#define NHT 16     // tokens per window (nh)
#define MD  128    // model dim
#define FFD 256    // ffn dim
#define NHEAD 4    // attention heads
#define DH  32     // head dim
#define PED 32     // pos-embed dim
#define ED  64     // input embed dim
#define LDT 132    // padded LDS stride for MD rows (avoid LN bank conflicts)
#define LDU 260    // padded LDS stride for FF rows
#define SCALE 0.17677669529663687f  // 1/sqrt(32)

__device__ __forceinline__ float silu_f(float x) {
    return x / (1.f + __expf(-x));
}

// LayerNorm over 16 rows of length 128 (stride LDT), in place.
// threads 0..15 each own one row (small fraction of total time).
__device__ __forceinline__ void ln_rows16(float* buf, const float* __restrict__ g,
                                          const float* __restrict__ b, int tid) {
    if (tid < NHT) {
        float* row = buf + tid * LDT;
        float s = 0.f, ss = 0.f;
        #pragma unroll
        for (int i = 0; i < MD; i += 4) {
            float4 v = *(const float4*)(row + i);
            s += v.x + v.y + v.z + v.w;
            ss = fmaf(v.x, v.x, ss); ss = fmaf(v.y, v.y, ss);
            ss = fmaf(v.z, v.z, ss); ss = fmaf(v.w, v.w, ss);
        }
        float m   = s * (1.f / MD);
        float var = ss * (1.f / MD) - m * m;
        float r   = rsqrtf(var + 1e-5f);
        #pragma unroll
        for (int i = 0; i < MD; i += 4) {
            float4 v  = *(const float4*)(row + i);
            float4 gv = *(const float4*)(g + i);
            float4 bv = *(const float4*)(b + i);
            v.x = fmaf((v.x - m) * r, gv.x, bv.x);
            v.y = fmaf((v.y - m) * r, gv.y, bv.y);
            v.z = fmaf((v.z - m) * r, gv.z, bv.z);
            v.w = fmaf((v.w - m) * r, gv.w, bv.w);
            *(float4*)(row + i) = v;
        }
    }
}

__global__ __launch_bounds__(128)
void nha_fused(const float* __restrict__ x,    const float* __restrict__ pos1,
               const float* __restrict__ pos2,
               const float* __restrict__ W_in, const float* __restrict__ g_in,
               const float* __restrict__ b_in,
               const float* __restrict__ W_pe, const float* __restrict__ W_bias,
               const float* __restrict__ Wq, const float* __restrict__ bq,
               const float* __restrict__ Wk, const float* __restrict__ bk,
               const float* __restrict__ Wv, const float* __restrict__ bv,
               const float* __restrict__ Wo, const float* __restrict__ bo,
               const float* __restrict__ W1, const float* __restrict__ W2,
               const float* __restrict__ g1, const float* __restrict__ b1,
               const float* __restrict__ g2, const float* __restrict__ b2,
               float* __restrict__ out) {
    // LDS: t/q/k/v rows [16][132] + sb (x staging 16*64, later bias 4*16*16)
    __shared__ __align__(16) float smem[4 * NHT * LDT + NHT * ED];
    float* t  = smem;               // 2112 floats
    float* qb = smem + 1 * NHT * LDT;
    float* kb = smem + 2 * NHT * LDT;
    float* vb = smem + 3 * NHT * LDT;
    float* sb = smem + 4 * NHT * LDT;   // 1024 floats
    float* ub = smem;               // FFN hidden [16][260] = 4160 floats, aliases t+qb (dead by then)

    const int tid = threadIdx.x;
    const int wi  = blockIdx.x;

    // ---- Stage A: load x window, z = x @ W_in -> t, LN ----
    for (int i = tid; i < NHT * ED; i += 128) sb[i] = x[wi * (NHT * ED) + i];
    __syncthreads();
    {
        const int j = tid;
        float acc[NHT];
        #pragma unroll
        for (int tok = 0; tok < NHT; ++tok) acc[tok] = 0.f;
        for (int k0 = 0; k0 < ED; k0 += 4) {
            float w0 = W_in[(k0 + 0) * MD + j];
            float w1 = W_in[(k0 + 1) * MD + j];
            float w2 = W_in[(k0 + 2) * MD + j];
            float w3 = W_in[(k0 + 3) * MD + j];
            #pragma unroll
            for (int tok = 0; tok < NHT; ++tok) {
                float4 xv = *(const float4*)(sb + tok * ED + k0);
                acc[tok] = fmaf(xv.x, w0, acc[tok]);
                acc[tok] = fmaf(xv.y, w1, acc[tok]);
                acc[tok] = fmaf(xv.z, w2, acc[tok]);
                acc[tok] = fmaf(xv.w, w3, acc[tok]);
            }
        }
        #pragma unroll
        for (int tok = 0; tok < NHT; ++tok) t[tok * LDT + j] = acc[tok];
    }
    __syncthreads();
    ln_rows16(t, g_in, b_in, tid);
    __syncthreads();

    // ---- Stage B: relative-position bias -> sb[h][qi][ki] (overwrites x staging) ----
    for (int p = tid; p < NHT * NHT; p += 128) {
        float p1 = pos1[wi * (NHT * NHT) + p];
        float p2 = pos2[wi * (NHT * NHT) + p];
        float a0 = 0.f, a1 = 0.f, a2 = 0.f, a3 = 0.f;
        #pragma unroll
        for (int i = 0; i < PED; ++i) {
            float e = fmaf(p1, W_pe[i], p2 * W_pe[PED + i]);
            float s = silu_f(e);
            a0 = fmaf(s, W_bias[i * NHEAD + 0], a0);
            a1 = fmaf(s, W_bias[i * NHEAD + 1], a1);
            a2 = fmaf(s, W_bias[i * NHEAD + 2], a2);
            a3 = fmaf(s, W_bias[i * NHEAD + 3], a3);
        }
        sb[0 * NHT * NHT + p] = a0;
        sb[1 * NHT * NHT + p] = a1;
        sb[2 * NHT * NHT + p] = a2;
        sb[3 * NHT * NHT + p] = a3;
    }

    // ---- Stage C: q,k,v = t @ W{q,k,v} + b (fused single k-loop) ----
    {
        const int j = tid;
        float aq[NHT], ak[NHT], av[NHT];
        const float bqj = bq[j], bkj = bk[j], bvj = bv[j];
        #pragma unroll
        for (int tok = 0; tok < NHT; ++tok) { aq[tok] = bqj; ak[tok] = bkj; av[tok] = bvj; }
        for (int k0 = 0; k0 < MD; k0 += 4) {
            float wq0 = Wq[(k0+0)*MD + j], wq1 = Wq[(k0+1)*MD + j], wq2 = Wq[(k0+2)*MD + j], wq3 = Wq[(k0+3)*MD + j];
            float wk0 = Wk[(k0+0)*MD + j], wk1 = Wk[(k0+1)*MD + j], wk2 = Wk[(k0+2)*MD + j], wk3 = Wk[(k0+3)*MD + j];
            float wv0 = Wv[(k0+0)*MD + j], wv1 = Wv[(k0+1)*MD + j], wv2 = Wv[(k0+2)*MD + j], wv3 = Wv[(k0+3)*MD + j];
            #pragma unroll
            for (int tok = 0; tok < NHT; ++tok) {
                float4 tv = *(const float4*)(t + tok * LDT + k0);
                aq[tok] = fmaf(tv.x, wq0, aq[tok]); aq[tok] = fmaf(tv.y, wq1, aq[tok]);
                aq[tok] = fmaf(tv.z, wq2, aq[tok]); aq[tok] = fmaf(tv.w, wq3, aq[tok]);
                ak[tok] = fmaf(tv.x, wk0, ak[tok]); ak[tok] = fmaf(tv.y, wk1, ak[tok]);
                ak[tok] = fmaf(tv.z, wk2, ak[tok]); ak[tok] = fmaf(tv.w, wk3, ak[tok]);
                av[tok] = fmaf(tv.x, wv0, av[tok]); av[tok] = fmaf(tv.y, wv1, av[tok]);
                av[tok] = fmaf(tv.z, wv2, av[tok]); av[tok] = fmaf(tv.w, wv3, av[tok]);
            }
        }
        #pragma unroll
        for (int tok = 0; tok < NHT; ++tok) {
            qb[tok * LDT + j] = aq[tok];
            kb[tok * LDT + j] = ak[tok];
            vb[tok * LDT + j] = av[tok];
        }
    }
    __syncthreads();

    // ---- Stage D: attention (64 lanes: one (head, q-row) each, all in registers) ----
    if (tid < NHEAD * NHT) {
        const int h = tid >> 4, qi = tid & 15;
        const float* qrow = qb + qi * LDT + h * DH;
        float qf[DH];
        #pragma unroll
        for (int d = 0; d < DH; d += 4) {
            float4 v = *(const float4*)(qrow + d);
            qf[d] = v.x; qf[d+1] = v.y; qf[d+2] = v.z; qf[d+3] = v.w;
        }
        float sc[NHT];
        #pragma unroll
        for (int ki = 0; ki < NHT; ++ki) {
            const float* krow = kb + ki * LDT + h * DH;
            float dot = 0.f;
            #pragma unroll
            for (int d = 0; d < DH; d += 4) {
                float4 kv = *(const float4*)(krow + d);
                dot = fmaf(qf[d], kv.x, dot);   dot = fmaf(qf[d+1], kv.y, dot);
                dot = fmaf(qf[d+2], kv.z, dot); dot = fmaf(qf[d+3], kv.w, dot);
            }
            sc[ki] = fmaf(dot, SCALE, sb[h * NHT * NHT + qi * NHT + ki]);
        }
        float m = sc[0];
        #pragma unroll
        for (int ki = 1; ki < NHT; ++ki) m = fmaxf(m, sc[ki]);
        float sum = 0.f;
        #pragma unroll
        for (int ki = 0; ki < NHT; ++ki) { sc[ki] = __expf(sc[ki] - m); sum += sc[ki]; }
        const float inv = 1.f / sum;
        float of[DH];
        #pragma unroll
        for (int d = 0; d < DH; ++d) of[d] = 0.f;
        #pragma unroll
        for (int ki = 0; ki < NHT; ++ki) {
            const float* vrow = vb + ki * LDT + h * DH;
            const float a = sc[ki];
            #pragma unroll
            for (int d = 0; d < DH; d += 4) {
                float4 vv = *(const float4*)(vrow + d);
                of[d]   = fmaf(a, vv.x, of[d]);   of[d+1] = fmaf(a, vv.y, of[d+1]);
                of[d+2] = fmaf(a, vv.z, of[d+2]); of[d+3] = fmaf(a, vv.w, of[d+3]);
            }
        }
        // write o into qb (each (h,qi) region is owned exclusively by this lane)
        float* orow = qb + qi * LDT + h * DH;
        #pragma unroll
        for (int d = 0; d < DH; d += 4) {
            float4 o4 = { of[d] * inv, of[d+1] * inv, of[d+2] * inv, of[d+3] * inv };
            *(float4*)(orow + d) = o4;
        }
    }
    __syncthreads();

    // ---- Stage E: att_out = o @ Wo + bo, residual + LN(g1,b1) -> kb ----
    {
        const int j = tid;
        float acc[NHT];
        const float boj = bo[j];
        #pragma unroll
        for (int tok = 0; tok < NHT; ++tok) acc[tok] = boj;
        for (int k0 = 0; k0 < MD; k0 += 4) {
            float w0 = Wo[(k0+0)*MD + j], w1 = Wo[(k0+1)*MD + j];
            float w2 = Wo[(k0+2)*MD + j], w3 = Wo[(k0+3)*MD + j];
            #pragma unroll
            for (int tok = 0; tok < NHT; ++tok) {
                float4 ov = *(const float4*)(qb + tok * LDT + k0);
                acc[tok] = fmaf(ov.x, w0, acc[tok]); acc[tok] = fmaf(ov.y, w1, acc[tok]);
                acc[tok] = fmaf(ov.z, w2, acc[tok]); acc[tok] = fmaf(ov.w, w3, acc[tok]);
            }
        }
        #pragma unroll
        for (int tok = 0; tok < NHT; ++tok)
            kb[tok * LDT + j] = acc[tok] + t[tok * LDT + j];
    }
    __syncthreads();
    ln_rows16(kb, g1, b1, tid);
    __syncthreads();

    // ---- Stage F: FFN1 u = silu(y @ W1) -> ub (aliases t/qb, both dead) ----
    {
        float a0[NHT], a1[NHT];   // columns tid and tid+128
        #pragma unroll
        for (int tok = 0; tok < NHT; ++tok) { a0[tok] = 0.f; a1[tok] = 0.f; }
        for (int k0 = 0; k0 < MD; k0 += 4) {
            float wa0 = W1[(k0+0)*FFD + tid],       wa1 = W1[(k0+1)*FFD + tid];
            float wa2 = W1[(k0+2)*FFD + tid],       wa3 = W1[(k0+3)*FFD + tid];
            float wb0 = W1[(k0+0)*FFD + tid + 128], wb1 = W1[(k0+1)*FFD + tid + 128];
            float wb2 = W1[(k0+2)*FFD + tid + 128], wb3 = W1[(k0+3)*FFD + tid + 128];
            #pragma unroll
            for (int tok = 0; tok < NHT; ++tok) {
                float4 yv = *(const float4*)(kb + tok * LDT + k0);
                a0[tok] = fmaf(yv.x, wa0, a0[tok]); a0[tok] = fmaf(yv.y, wa1, a0[tok]);
                a0[tok] = fmaf(yv.z, wa2, a0[tok]); a0[tok] = fmaf(yv.w, wa3, a0[tok]);
                a1[tok] = fmaf(yv.x, wb0, a1[tok]); a1[tok] = fmaf(yv.y, wb1, a1[tok]);
                a1[tok] = fmaf(yv.z, wb2, a1[tok]); a1[tok] = fmaf(yv.w, wb3, a1[tok]);
            }
        }
        #pragma unroll
        for (int tok = 0; tok < NHT; ++tok) {
            ub[tok * LDU + tid]       = silu_f(a0[tok]);
            ub[tok * LDU + tid + 128] = silu_f(a1[tok]);
        }
    }
    __syncthreads();

    // ---- Stage G: FFN2 + residual -> vb, LN(g2,b2), write out ----
    {
        const int j = tid;
        float acc[NHT];
        #pragma unroll
        for (int tok = 0; tok < NHT; ++tok) acc[tok] = 0.f;
        for (int k0 = 0; k0 < FFD; k0 += 4) {
            float w0 = W2[(k0+0)*MD + j], w1 = W2[(k0+1)*MD + j];
            float w2 = W2[(k0+2)*MD + j], w3 = W2[(k0+3)*MD + j];
            #pragma unroll
            for (int tok = 0; tok < NHT; ++tok) {
                float4 uv = *(const float4*)(ub + tok * LDU + k0);
                acc[tok] = fmaf(uv.x, w0, acc[tok]); acc[tok] = fmaf(uv.y, w1, acc[tok]);
                acc[tok] = fmaf(uv.z, w2, acc[tok]); acc[tok] = fmaf(uv.w, w3, acc[tok]);
            }
        }
        #pragma unroll
        for (int tok = 0; tok < NHT; ++tok)
            vb[tok * LDT + j] = acc[tok] + kb[tok * LDT + j];
    }
    __syncthreads();
    ln_rows16(vb, g2, b2, tid);
    __syncthreads();

    for (int i = tid; i < NHT * MD; i += 128) {
        int tok = i >> 7, j5 = i & 127;
        out[wi * (NHT * MD) + i] = vb[tok * LDT + j5];
    }
}

extern "C" void kernel_launch(void* const* d_in, const int* in_sizes, int n_in,
                              void* d_out, int out_size, void* d_ws, size_t ws_size,
                              hipStream_t stream) {
    const float* x     = (const float*)d_in[0];
    const float* pos1  = (const float*)d_in[1];
    const float* pos2  = (const float*)d_in[2];
    const float* W_in  = (const float*)d_in[3];
    const float* g_in  = (const float*)d_in[4];
    const float* b_in  = (const float*)d_in[5];
    const float* W_pe  = (const float*)d_in[6];
    const float* W_bias= (const float*)d_in[7];
    const float* Wq    = (const float*)d_in[8];
    const float* bq    = (const float*)d_in[9];
    const float* Wk    = (const float*)d_in[10];
    const float* bk    = (const float*)d_in[11];
    const float* Wv    = (const float*)d_in[12];
    const float* bv    = (const float*)d_in[13];
    const float* Wo    = (const float*)d_in[14];
    const float* bo    = (const float*)d_in[15];
    const float* W1    = (const float*)d_in[16];
    const float* W2    = (const float*)d_in[17];
    const float* g1    = (const float*)d_in[18];
    const float* b1    = (const float*)d_in[19];
    const float* g2    = (const float*)d_in[20];
    const float* b2    = (const float*)d_in[21];
    float* out = (float*)d_out;

    const int nwin = in_sizes[0] / (NHT * ED);   // B*N = 16384
    nha_fused<<<nwin, 128, 0, stream>>>(x, pos1, pos2, W_in, g_in, b_in, W_pe, W_bias,
                                        Wq, bq, Wk, bk, Wv, bv, Wo, bo,
                                        W1, W2, g1, b1, g2, b2, out);
}